// Round 1
// baseline (455.460 us; speedup 1.0000x reference)
//
#include <hip/hip_runtime.h>
#include <cstdint>

// Problem constants (from reference setup_inputs)
#define BB   64      // batch
#define SS   20      // max_seq
#define WW   1024    // num_words
#define NCC  80      // num_cls
#define DLL  300     // dim_latent
#define DEE  128     // dim_embed
#define KMAX 20

// d_out float offsets (outputs concatenated flat in return order)
#define O_OUT   0
#define O_FEAT  (BB*NCC)                        // 5120
#define O_WP    (O_FEAT + BB*DEE)               // 13312
#define O_ADJ   (O_WP + BB*WW)                  // 78848
#define O_WPROB ((size_t)O_ADJ + (size_t)BB*WW*WW)  // 67187712

// workspace float offsets
#define WS_V    0                    // [B][DE] = 8192
#define WS_S0   (WS_V + BB*DEE)      // 128
#define WS_S1   (WS_S0 + DEE)        // 128
#define WS_N1   (WS_S1 + DEE)        // 64
#define WS_MHT  (WS_N1 + 64)         // [W][B] float 0/1 = 65536
#define WS_WPT  (WS_MHT + WW*BB)     // [W][B] = 65536
#define WS_P    (WS_WPT + WW*BB)     // [512][B][DE] = 4194304 floats (16 MB)
#define MM_BLOCKS 512

__device__ __forceinline__ void amax2(float& v, int& i, float ov, int oi) {
    if (ov > v || (ov == v && oi < i)) { v = ov; i = oi; }
}

__device__ __forceinline__ float lrelu(float x) {
    return x >= 0.f ? x : 0.01f * x;
}

// ---------------------------------------------------------------------------
// K1: per-batch prep. One block per batch sample.
//  argmax->multi_hot (first-k, first-index tie-break), unique id list,
//  softmax logits -> weight_cls, weight_pri (-> d_out), sw1/swall,
//  s0/s1 (support rows for emb idx 0/1), v[b][e], word_prob copy.
// ---------------------------------------------------------------------------
__global__ __launch_bounds__(256) void k1_prep(
    const float* __restrict__ word_recon, const float* __restrict__ metrix_sl,
    const float* __restrict__ cls_word_prob, const float* __restrict__ emb,
    const float* __restrict__ w_sl, const float* __restrict__ b_sl,
    const float* __restrict__ w_lw, const float* __restrict__ b_lw,
    const int* __restrict__ label, const int* __restrict__ kptr,
    float* __restrict__ out, float* __restrict__ ws)
{
    const int b = blockIdx.x, t = threadIdx.x;
    __shared__ __align__(16) float l_mh[WW];
    __shared__ __align__(16) float l_wp[WW];
    __shared__ float l_wc[NCC];
    __shared__ __align__(16) float l_s0[DEE];
    __shared__ __align__(16) float l_s1[DEE];
    __shared__ int   l_ids[KMAX];
    __shared__ int   l_cnt;
    __shared__ float l_av[4];
    __shared__ int   l_ai[4];
    __shared__ float l_red[4];
    __shared__ float l_max, l_sum, l_sw1, l_swall;

    for (int w = t; w < WW; w += 256) l_mh[w] = 0.f;
    if (t == 0) l_cnt = 0;
    __syncthreads();

    int kk = kptr[0];
    if (kk > SS) kk = SS;
    if (kk > KMAX) kk = KMAX;

    // argmax per timestep, set multi_hot, collect unique ids
    for (int s = 0; s < kk; ++s) {
        const float* row = word_recon + ((size_t)b * SS + s) * WW;
        float4 x = *(const float4*)(row + t * 4);
        float bv = x.x; int bi = t * 4;
        amax2(bv, bi, x.y, t * 4 + 1);
        amax2(bv, bi, x.z, t * 4 + 2);
        amax2(bv, bi, x.w, t * 4 + 3);
        for (int off = 32; off >= 1; off >>= 1) {
            float ov = __shfl_down(bv, off);
            int   oi = __shfl_down(bi, off);
            amax2(bv, bi, ov, oi);
        }
        if ((t & 63) == 0) { l_av[t >> 6] = bv; l_ai[t >> 6] = bi; }
        __syncthreads();
        if (t == 0) {
            float v0 = l_av[0]; int i0 = l_ai[0];
            amax2(v0, i0, l_av[1], l_ai[1]);
            amax2(v0, i0, l_av[2], l_ai[2]);
            amax2(v0, i0, l_av[3], l_ai[3]);
            if (l_mh[i0] == 0.f) { l_mh[i0] = 1.f; l_ids[l_cnt++] = i0; }
        }
        __syncthreads();
    }
    const int n1 = l_cnt;

    // store mh transposed [w][b] + n1
    {
        float* mh_T = ws + WS_MHT;
        for (int w = t; w < WW; w += 256) mh_T[w * BB + b] = l_mh[w];
        if (t == 0) (ws + WS_N1)[b] = (float)n1;
    }

    // logits over classes: sum of w_sl[c, selected] (+ b_sl)
    if (t < NCC) {
        float lg = b_sl[t];
        for (int u = 0; u < n1; ++u) lg += w_sl[t * WW + l_ids[u]];
        l_wc[t] = lg;
    }
    __syncthreads();
    if (t == 0) {
        float m = l_wc[0];
        for (int c = 1; c < NCC; ++c) m = fmaxf(m, l_wc[c]);
        l_max = m;
    }
    __syncthreads();
    if (t < NCC) l_wc[t] = expf(l_wc[t] - l_max);
    __syncthreads();
    if (t == 0) {
        float s = 0.f;
        for (int c = 0; c < NCC; ++c) s += l_wc[c];
        l_sum = s;
    }
    __syncthreads();
    if (t < NCC) l_wc[t] = l_wc[t] / l_sum;
    __syncthreads();

    // weight_pri[b,:] = weight_cls @ metrix_sl   (and row-sum for swall)
    float swpart;
    {
        int w4 = t * 4;
        float4 acc = {0.f, 0.f, 0.f, 0.f};
        for (int c = 0; c < NCC; ++c) {
            float wc = l_wc[c];
            float4 m4 = *(const float4*)(metrix_sl + c * WW + w4);
            acc.x += wc * m4.x; acc.y += wc * m4.y;
            acc.z += wc * m4.z; acc.w += wc * m4.w;
        }
        *(float4*)(out + O_WP + b * WW + w4) = acc;      // output 2
        *(float4*)(&l_wp[w4]) = acc;
        float* wp_T = ws + WS_WPT;
        wp_T[(w4 + 0) * BB + b] = acc.x;
        wp_T[(w4 + 1) * BB + b] = acc.y;
        wp_T[(w4 + 2) * BB + b] = acc.z;
        wp_T[(w4 + 3) * BB + b] = acc.w;
        swpart = acc.x + acc.y + acc.z + acc.w;
    }
    for (int off = 32; off >= 1; off >>= 1) swpart += __shfl_down(swpart, off);
    if ((t & 63) == 0) l_red[t >> 6] = swpart;
    __syncthreads();
    if (t == 0) {
        float sa = l_red[0] + l_red[1] + l_red[2] + l_red[3];
        float s1v = 0.f;
        for (int u = 0; u < n1; ++u) s1v += l_wp[l_ids[u]];
        l_swall = sa; l_sw1 = s1v;
    }
    __syncthreads();

    // s0/s1 = support rows for embedding index 0/1 (incl. b_lw)
    if (t < DEE) {
        float a0 = b_lw[t], a1 = b_lw[t];
        const float* wl = w_lw + t * DLL;
        for (int l = 0; l < DLL; l += 4) {
            float4 wv = *(const float4*)(wl + l);
            float4 e0 = *(const float4*)(emb + l);
            float4 e1 = *(const float4*)(emb + DLL + l);
            a0 += wv.x * e0.x + wv.y * e0.y + wv.z * e0.z + wv.w * e0.w;
            a1 += wv.x * e1.x + wv.y * e1.y + wv.z * e1.z + wv.w * e1.w;
        }
        l_s0[t] = a0; l_s1[t] = a1;
        if (b == 0) { (ws + WS_S0)[t] = a0; (ws + WS_S1)[t] = a1; }
    }
    __syncthreads();

    // v[b][e] = s1*sw1 + s0*(swall - sw1)
    if (t < DEE) {
        float sw1 = l_sw1, sw0 = l_swall - l_sw1;
        (ws + WS_V)[b * DEE + t] = l_s1[t] * sw1 + l_s0[t] * sw0;
    }

    // word_prob = cls_word_prob[label[b]]  (output 4)
    {
        int lbl = label[b];
        int w4 = t * 4;
        float4 p4 = *(const float4*)(cls_word_prob + (size_t)lbl * WW + w4);
        *(float4*)(out + O_WPROB + (size_t)b * WW + w4) = p4;
    }
}

// ---------------------------------------------------------------------------
// K2: adj_pri[b,i,j] = wp[b,i]*wp[b,j]  — 268 MB pure-write kernel.
// 8192 blocks x 8 rows each; row r = b*1024+i; coalesced float4 stores.
// ---------------------------------------------------------------------------
__global__ __launch_bounds__(256) void k_adj(
    const float* __restrict__ wp, float* __restrict__ adj)
{
    const int t = threadIdx.x;
    const int base_row = blockIdx.x * 8;
#pragma unroll
    for (int n = 0; n < 8; ++n) {
        int r = base_row + n;
        int b = r >> 10, i = r & 1023;
        float wi = wp[b * WW + i];
        float4 v4 = *(const float4*)(wp + b * WW + t * 4);
        float4 o;
        o.x = wi * v4.x; o.y = wi * v4.y; o.z = wi * v4.z; o.w = wi * v4.w;
        *(float4*)(adj + ((size_t)r << 10) + t * 4) = o;
    }
}

// ---------------------------------------------------------------------------
// K3: split-K matmul  partial[blk][b][d] = sum_{i in chunk} F_i[b,:] . G_i[d,:]
//  F_i computed on the fly into LDS (closed-form feat1, incl. leaky_relu).
//  w_gcn element read exactly once chip-wide (16-lane broadcast per float4).
// ---------------------------------------------------------------------------
__global__ __launch_bounds__(256) void k_mm(
    const float* __restrict__ w_gcn, const float* __restrict__ beta_p,
    const float* __restrict__ vv, const float* __restrict__ s0g,
    const float* __restrict__ s1g, const float* __restrict__ n1g,
    const float* __restrict__ mh_T, const float* __restrict__ wp_T,
    float* __restrict__ P)
{
    __shared__ __align__(16) float F[DEE * BB];   // F[e][b], 32 KB
    __shared__ __align__(16) float s0s[DEE];
    __shared__ __align__(16) float s1s[DEE];
    const int t = threadIdx.x;
    if (t < DEE) { s0s[t] = s0g[t]; s1s[t] = s1g[t]; }
    const float beta = beta_p[0];
    const float omb = 1.f - beta;

    float c[4][8];
#pragma unroll
    for (int a = 0; a < 4; ++a)
#pragma unroll
        for (int q = 0; q < 8; ++q) c[a][q] = 0.f;

    const int b0 = (t & 15) * 4;       // C-tile: 4 batches
    const int d0 = (t >> 4) * 8;       // C-tile: 8 outputs
    const int fb = t >> 2;             // F-compute: batch
    const int e0 = (t & 3) * 32;       // F-compute: e-range
    __syncthreads();

    for (int ii = 0; ii < 2; ++ii) {
        const int i = blockIdx.x * 2 + ii;
        // --- compute F_i into LDS ---
        {
            float p    = mh_T[i * BB + fb];           // 0/1
            float wpbi = wp_T[i * BB + fb];
            float n1   = n1g[fb];
            float a1 = omb * p * n1;
            float a0 = omb * (1.f - p);
            float g  = beta * wpbi;
#pragma unroll
            for (int q = 0; q < 32; q += 4) {
                int e = e0 + q;
                float4 v4  = *(const float4*)(vv + fb * DEE + e);
                float4 s04 = *(const float4*)(&s0s[e]);
                float4 s14 = *(const float4*)(&s1s[e]);
                F[(e + 0) * BB + fb] = lrelu(a1 * s14.x + a0 * s04.x + g * v4.x);
                F[(e + 1) * BB + fb] = lrelu(a1 * s14.y + a0 * s04.y + g * v4.y);
                F[(e + 2) * BB + fb] = lrelu(a1 * s14.z + a0 * s04.z + g * v4.z);
                F[(e + 3) * BB + fb] = lrelu(a1 * s14.w + a0 * s04.w + g * v4.w);
            }
        }
        __syncthreads();
        // --- accumulate C += F_i @ G_i^T ---
        const float* gbase = w_gcn + (size_t)i * DEE;
#pragma unroll 2
        for (int e4 = 0; e4 < 32; ++e4) {
            int e = e4 * 4;
            float4 f0 = *(const float4*)(&F[(e + 0) * BB + b0]);
            float4 f1 = *(const float4*)(&F[(e + 1) * BB + b0]);
            float4 f2 = *(const float4*)(&F[(e + 2) * BB + b0]);
            float4 f3 = *(const float4*)(&F[(e + 3) * BB + b0]);
#pragma unroll
            for (int q = 0; q < 8; ++q) {
                float4 g4 = *(const float4*)(gbase + (size_t)(d0 + q) * (DEE * WW) + e);
                c[0][q] += f0.x * g4.x + f1.x * g4.y + f2.x * g4.z + f3.x * g4.w;
                c[1][q] += f0.y * g4.x + f1.y * g4.y + f2.y * g4.z + f3.y * g4.w;
                c[2][q] += f0.z * g4.x + f1.z * g4.y + f2.z * g4.z + f3.z * g4.w;
                c[3][q] += f0.w * g4.x + f1.w * g4.y + f2.w * g4.z + f3.w * g4.w;
            }
        }
        __syncthreads();
    }

    float* pb = P + (size_t)blockIdx.x * (BB * DEE);
#pragma unroll
    for (int jb = 0; jb < 4; ++jb) {
        float4 lo = {c[jb][0], c[jb][1], c[jb][2], c[jb][3]};
        float4 hi = {c[jb][4], c[jb][5], c[jb][6], c[jb][7]};
        *(float4*)(pb + (b0 + jb) * DEE + d0)     = lo;
        *(float4*)(pb + (b0 + jb) * DEE + d0 + 4) = hi;
    }
}

// ---------------------------------------------------------------------------
// K4: reduce split-K partials, + b_gcn, leaky_relu -> feat (output 1),
//     then output = feat @ w_cls.T + b_cls (output 0). One block per batch.
// ---------------------------------------------------------------------------
__global__ __launch_bounds__(1024) void k_red(
    const float* __restrict__ P, const float* __restrict__ b_gcn,
    const float* __restrict__ w_cls, const float* __restrict__ b_cls,
    float* __restrict__ out)
{
    const int b = blockIdx.x, t = threadIdx.x;
    const int d = t & 127, pg = t >> 7;   // 8 p-groups of 64
    __shared__ float red[8][DEE];
    __shared__ __align__(16) float lf[DEE];

    const float* pp = P + (size_t)pg * 64 * (BB * DEE) + b * DEE + d;
    float a0 = 0.f, a1 = 0.f, a2 = 0.f, a3 = 0.f;
    for (int p = 0; p < 64; p += 4) {
        a0 += pp[(size_t)(p + 0) * (BB * DEE)];
        a1 += pp[(size_t)(p + 1) * (BB * DEE)];
        a2 += pp[(size_t)(p + 2) * (BB * DEE)];
        a3 += pp[(size_t)(p + 3) * (BB * DEE)];
    }
    red[pg][d] = (a0 + a1) + (a2 + a3);
    __syncthreads();
    if (t < DEE) {
        float s = 0.f;
#pragma unroll
        for (int g = 0; g < 8; ++g) s += red[g][t];
        s += b_gcn[t];
        s = lrelu(s);
        out[O_FEAT + b * DEE + t] = s;   // output 1
        lf[t] = s;
    }
    __syncthreads();
    if (t < NCC) {
        float o = b_cls[t];
        const float* wc = w_cls + t * DEE;
        for (int d2 = 0; d2 < DEE; d2 += 4) {
            float4 w4 = *(const float4*)(wc + d2);
            o += w4.x * lf[d2] + w4.y * lf[d2 + 1] + w4.z * lf[d2 + 2] + w4.w * lf[d2 + 3];
        }
        out[b * NCC + t] = o;            // output 0
    }
}

extern "C" void kernel_launch(void* const* d_in, const int* in_sizes, int n_in,
                              void* d_out, int out_size, void* d_ws, size_t ws_size,
                              hipStream_t stream) {
    const float* word_recon    = (const float*)d_in[0];
    const float* beta_p        = (const float*)d_in[1];
    const float* metrix_sl     = (const float*)d_in[2];
    const float* cls_word_prob = (const float*)d_in[3];
    const float* emb           = (const float*)d_in[4];
    const float* w_sl          = (const float*)d_in[5];
    const float* b_sl          = (const float*)d_in[6];
    const float* w_lw          = (const float*)d_in[7];
    const float* b_lw          = (const float*)d_in[8];
    const float* w_gcn         = (const float*)d_in[9];
    const float* b_gcn         = (const float*)d_in[10];
    const float* w_cls         = (const float*)d_in[11];
    const float* b_cls         = (const float*)d_in[12];
    const int*   label         = (const int*)d_in[13];
    const int*   kptr          = (const int*)d_in[14];
    float* out = (float*)d_out;
    float* ws  = (float*)d_ws;

    k1_prep<<<BB, 256, 0, stream>>>(word_recon, metrix_sl, cls_word_prob, emb,
                                    w_sl, b_sl, w_lw, b_lw, label, kptr, out, ws);
    k_adj<<<(BB * WW) / 8, 256, 0, stream>>>(out + O_WP, out + O_ADJ);
    k_mm<<<MM_BLOCKS, 256, 0, stream>>>(w_gcn, beta_p, ws + WS_V, ws + WS_S0,
                                        ws + WS_S1, ws + WS_N1, ws + WS_MHT,
                                        ws + WS_WPT, ws + WS_P);
    k_red<<<BB, 1024, 0, stream>>>(ws + WS_P, b_gcn, w_cls, b_cls, out);
}

// Round 4
// 449.916 us; speedup vs baseline: 1.0123x; 1.0123x over previous
//
#include <hip/hip_runtime.h>
#include <cstdint>

// Problem constants (from reference setup_inputs)
#define BB   64      // batch
#define SS   20      // max_seq
#define WW   1024    // num_words
#define NCC  80      // num_cls
#define DLL  300     // dim_latent
#define DEE  128     // dim_embed
#define KMAX 20

// d_out float offsets (outputs concatenated flat in return order)
#define O_OUT   0
#define O_FEAT  (BB*NCC)                        // 5120
#define O_WP    (O_FEAT + BB*DEE)               // 13312
#define O_ADJ   (O_WP + BB*WW)                  // 78848
#define O_WPROB ((size_t)O_ADJ + (size_t)BB*WW*WW)  // 67187712

// workspace float offsets
#define WS_V    0                    // [B][DE] = 8192
#define WS_S0   (WS_V + BB*DEE)      // 128
#define WS_S1   (WS_S0 + DEE)        // 128
#define WS_N1   (WS_S1 + DEE)        // 64
#define WS_MHT  (WS_N1 + 64)         // [W][B] float 0/1 = 65536
#define WS_WPT  (WS_MHT + WW*BB)     // [W][B] = 65536
#define WS_P    (WS_WPT + WW*BB)     // [512][B][DE] = 4194304 floats (16 MB)
#define MM_BLOCKS 512

// native clang vector for nontemporal stores (HIP float4 is a class type)
typedef float nfloat4 __attribute__((ext_vector_type(4)));

__device__ __forceinline__ void amax2(float& v, int& i, float ov, int oi) {
    if (ov > v || (ov == v && oi < i)) { v = ov; i = oi; }
}

__device__ __forceinline__ float lrelu(float x) {
    return x >= 0.f ? x : 0.01f * x;
}

// ---------------------------------------------------------------------------
// K1: per-batch prep. One block per batch sample.
// ---------------------------------------------------------------------------
__global__ __launch_bounds__(256) void k1_prep(
    const float* __restrict__ word_recon, const float* __restrict__ metrix_sl,
    const float* __restrict__ cls_word_prob, const float* __restrict__ emb,
    const float* __restrict__ w_sl, const float* __restrict__ b_sl,
    const float* __restrict__ w_lw, const float* __restrict__ b_lw,
    const int* __restrict__ label, const int* __restrict__ kptr,
    float* __restrict__ out, float* __restrict__ ws)
{
    const int b = blockIdx.x, t = threadIdx.x;
    __shared__ __align__(16) float l_mh[WW];
    __shared__ __align__(16) float l_wp[WW];
    __shared__ float l_wc[NCC];
    __shared__ __align__(16) float l_s0[DEE];
    __shared__ __align__(16) float l_s1[DEE];
    __shared__ int   l_ids[KMAX];
    __shared__ int   l_cnt;
    __shared__ float l_av[4];
    __shared__ int   l_ai[4];
    __shared__ float l_red[4];
    __shared__ float l_max, l_sum, l_sw1, l_swall;

    for (int w = t; w < WW; w += 256) l_mh[w] = 0.f;
    if (t == 0) l_cnt = 0;
    __syncthreads();

    int kk = kptr[0];
    if (kk > SS) kk = SS;
    if (kk > KMAX) kk = KMAX;

    // argmax per timestep, set multi_hot, collect unique ids
    for (int s = 0; s < kk; ++s) {
        const float* row = word_recon + ((size_t)b * SS + s) * WW;
        float4 x = *(const float4*)(row + t * 4);
        float bv = x.x; int bi = t * 4;
        amax2(bv, bi, x.y, t * 4 + 1);
        amax2(bv, bi, x.z, t * 4 + 2);
        amax2(bv, bi, x.w, t * 4 + 3);
        for (int off = 32; off >= 1; off >>= 1) {
            float ov = __shfl_down(bv, off);
            int   oi = __shfl_down(bi, off);
            amax2(bv, bi, ov, oi);
        }
        if ((t & 63) == 0) { l_av[t >> 6] = bv; l_ai[t >> 6] = bi; }
        __syncthreads();
        if (t == 0) {
            float v0 = l_av[0]; int i0 = l_ai[0];
            amax2(v0, i0, l_av[1], l_ai[1]);
            amax2(v0, i0, l_av[2], l_ai[2]);
            amax2(v0, i0, l_av[3], l_ai[3]);
            if (l_mh[i0] == 0.f) { l_mh[i0] = 1.f; l_ids[l_cnt++] = i0; }
        }
        __syncthreads();
    }
    const int n1 = l_cnt;

    // store mh transposed [w][b] + n1
    {
        float* mh_T = ws + WS_MHT;
        for (int w = t; w < WW; w += 256) mh_T[w * BB + b] = l_mh[w];
        if (t == 0) (ws + WS_N1)[b] = (float)n1;
    }

    // logits over classes: sum of w_sl[c, selected] (+ b_sl)
    if (t < NCC) {
        float lg = b_sl[t];
        for (int u = 0; u < n1; ++u) lg += w_sl[t * WW + l_ids[u]];
        l_wc[t] = lg;
    }
    __syncthreads();
    if (t == 0) {
        float m = l_wc[0];
        for (int c = 1; c < NCC; ++c) m = fmaxf(m, l_wc[c]);
        l_max = m;
    }
    __syncthreads();
    if (t < NCC) l_wc[t] = expf(l_wc[t] - l_max);
    __syncthreads();
    if (t == 0) {
        float s = 0.f;
        for (int c = 0; c < NCC; ++c) s += l_wc[c];
        l_sum = s;
    }
    __syncthreads();
    if (t < NCC) l_wc[t] = l_wc[t] / l_sum;
    __syncthreads();

    // weight_pri[b,:] = weight_cls @ metrix_sl   (and row-sum for swall)
    float swpart;
    {
        int w4 = t * 4;
        float4 acc = {0.f, 0.f, 0.f, 0.f};
        for (int c = 0; c < NCC; ++c) {
            float wc = l_wc[c];
            float4 m4 = *(const float4*)(metrix_sl + c * WW + w4);
            acc.x += wc * m4.x; acc.y += wc * m4.y;
            acc.z += wc * m4.z; acc.w += wc * m4.w;
        }
        *(float4*)(out + O_WP + b * WW + w4) = acc;      // output 2
        *(float4*)(&l_wp[w4]) = acc;
        float* wp_T = ws + WS_WPT;
        wp_T[(w4 + 0) * BB + b] = acc.x;
        wp_T[(w4 + 1) * BB + b] = acc.y;
        wp_T[(w4 + 2) * BB + b] = acc.z;
        wp_T[(w4 + 3) * BB + b] = acc.w;
        swpart = acc.x + acc.y + acc.z + acc.w;
    }
    for (int off = 32; off >= 1; off >>= 1) swpart += __shfl_down(swpart, off);
    if ((t & 63) == 0) l_red[t >> 6] = swpart;
    __syncthreads();
    if (t == 0) {
        float sa = l_red[0] + l_red[1] + l_red[2] + l_red[3];
        float s1v = 0.f;
        for (int u = 0; u < n1; ++u) s1v += l_wp[l_ids[u]];
        l_swall = sa; l_sw1 = s1v;
    }
    __syncthreads();

    // s0/s1 = support rows for embedding index 0/1 (incl. b_lw)
    if (t < DEE) {
        float a0 = b_lw[t], a1 = b_lw[t];
        const float* wl = w_lw + t * DLL;
        for (int l = 0; l < DLL; l += 4) {
            float4 wv = *(const float4*)(wl + l);
            float4 e0 = *(const float4*)(emb + l);
            float4 e1 = *(const float4*)(emb + DLL + l);
            a0 += wv.x * e0.x + wv.y * e0.y + wv.z * e0.z + wv.w * e0.w;
            a1 += wv.x * e1.x + wv.y * e1.y + wv.z * e1.z + wv.w * e1.w;
        }
        l_s0[t] = a0; l_s1[t] = a1;
        if (b == 0) { (ws + WS_S0)[t] = a0; (ws + WS_S1)[t] = a1; }
    }
    __syncthreads();

    // v[b][e] = s1*sw1 + s0*(swall - sw1)
    if (t < DEE) {
        float sw1 = l_sw1, sw0 = l_swall - l_sw1;
        (ws + WS_V)[b * DEE + t] = l_s1[t] * sw1 + l_s0[t] * sw0;
    }

    // word_prob = cls_word_prob[label[b]]  (output 4)
    {
        int lbl = label[b];
        int w4 = t * 4;
        float4 p4 = *(const float4*)(cls_word_prob + (size_t)lbl * WW + w4);
        *(float4*)(out + O_WPROB + (size_t)b * WW + w4) = p4;
    }
}

// ---------------------------------------------------------------------------
// K2 (fused): split-K matmul + adj_pri writer.
//  512 blocks. Each block:
//   - computes partial[blk][b][d] over its 2 w_gcn column-chunks (i = blk*2+ii),
//     with F_i (closed-form feat1 incl. leaky_relu) built in LDS on the fly;
//   - writes its 128 adj_pri rows (512 KB, nontemporal), 2 rows per e4
//     iteration so the 268 MB write drain overlaps the FMA/load stream.
//  128 rows per block share one batch index (128 | 1024): wrow loaded once,
//  the 128 row scalars staged in LDS.
// ---------------------------------------------------------------------------
__global__ __launch_bounds__(256) void k_fused(
    const float* __restrict__ w_gcn, const float* __restrict__ beta_p,
    const float* __restrict__ vv, const float* __restrict__ s0g,
    const float* __restrict__ s1g, const float* __restrict__ n1g,
    const float* __restrict__ mh_T, const float* __restrict__ wp_T,
    const float* __restrict__ wp, float* __restrict__ adj,
    float* __restrict__ P)
{
    __shared__ __align__(16) float F[DEE * BB];   // F[e][b], 32 KB
    __shared__ __align__(16) float s0s[DEE];
    __shared__ __align__(16) float s1s[DEE];
    __shared__ __align__(16) float wi_s[128];
    const int t = threadIdx.x;
    if (t < DEE) { s0s[t] = s0g[t]; s1s[t] = s1g[t]; }
    const float beta = beta_p[0];
    const float omb = 1.f - beta;

    // adj assignment: rows r = b_adj*1024 + i0_adj + [0,128)
    const int b_adj  = blockIdx.x >> 3;          // 512 blocks / 8 per batch
    const int i0_adj = (blockIdx.x & 7) * 128;
    if (t < 128) wi_s[t] = wp[b_adj * WW + i0_adj + t];
    const float4 wrow = *(const float4*)(wp + b_adj * WW + t * 4);

    float c[4][8];
#pragma unroll
    for (int a = 0; a < 4; ++a)
#pragma unroll
        for (int q = 0; q < 8; ++q) c[a][q] = 0.f;

    const int b0 = (t & 15) * 4;       // C-tile: 4 batches
    const int d0 = (t >> 4) * 8;       // C-tile: 8 outputs
    const int fb = t >> 2;             // F-compute: batch
    const int e0 = (t & 3) * 32;       // F-compute: e-range
    __syncthreads();

    for (int ii = 0; ii < 2; ++ii) {
        const int i = blockIdx.x * 2 + ii;
        // --- compute F_i into LDS ---
        {
            float p    = mh_T[i * BB + fb];           // 0/1
            float wpbi = wp_T[i * BB + fb];
            float n1   = n1g[fb];
            float a1 = omb * p * n1;
            float a0 = omb * (1.f - p);
            float g  = beta * wpbi;
#pragma unroll
            for (int q = 0; q < 32; q += 4) {
                int e = e0 + q;
                float4 v4  = *(const float4*)(vv + fb * DEE + e);
                float4 s04 = *(const float4*)(&s0s[e]);
                float4 s14 = *(const float4*)(&s1s[e]);
                F[(e + 0) * BB + fb] = lrelu(a1 * s14.x + a0 * s04.x + g * v4.x);
                F[(e + 1) * BB + fb] = lrelu(a1 * s14.y + a0 * s04.y + g * v4.y);
                F[(e + 2) * BB + fb] = lrelu(a1 * s14.z + a0 * s04.z + g * v4.z);
                F[(e + 3) * BB + fb] = lrelu(a1 * s14.w + a0 * s04.w + g * v4.w);
            }
        }
        __syncthreads();

        // --- accumulate C += F_i @ G_i^T, with 2 adj_pri row stores per
        //     iteration (64 rows per phase, 128 per block total) ---
        const float* gbase = w_gcn + (size_t)i * DEE;
        const size_t rbase = ((size_t)(b_adj << 10) + i0_adj + ii * 64);
#pragma unroll 2
        for (int e4 = 0; e4 < 32; ++e4) {
            // two fire-and-forget adj rows
            {
                const int n0 = e4 * 2;
#pragma unroll
                for (int n = 0; n < 2; ++n) {
                    const float wi = wi_s[ii * 64 + n0 + n];
                    nfloat4 o;
                    o.x = wi * wrow.x; o.y = wi * wrow.y;
                    o.z = wi * wrow.z; o.w = wi * wrow.w;
                    __builtin_nontemporal_store(
                        o, (nfloat4*)(adj + ((rbase + n0 + n) << 10) + t * 4));
                }
            }
            int e = e4 * 4;
            float4 f0 = *(const float4*)(&F[(e + 0) * BB + b0]);
            float4 f1 = *(const float4*)(&F[(e + 1) * BB + b0]);
            float4 f2 = *(const float4*)(&F[(e + 2) * BB + b0]);
            float4 f3 = *(const float4*)(&F[(e + 3) * BB + b0]);
#pragma unroll
            for (int q = 0; q < 8; ++q) {
                float4 g4 = *(const float4*)(gbase + (size_t)(d0 + q) * (DEE * WW) + e);
                c[0][q] += f0.x * g4.x + f1.x * g4.y + f2.x * g4.z + f3.x * g4.w;
                c[1][q] += f0.y * g4.x + f1.y * g4.y + f2.y * g4.z + f3.y * g4.w;
                c[2][q] += f0.z * g4.x + f1.z * g4.y + f2.z * g4.z + f3.z * g4.w;
                c[3][q] += f0.w * g4.x + f1.w * g4.y + f2.w * g4.z + f3.w * g4.w;
            }
        }
        __syncthreads();
    }

    float* pb = P + (size_t)blockIdx.x * (BB * DEE);
#pragma unroll
    for (int jb = 0; jb < 4; ++jb) {
        float4 lo = {c[jb][0], c[jb][1], c[jb][2], c[jb][3]};
        float4 hi = {c[jb][4], c[jb][5], c[jb][6], c[jb][7]};
        *(float4*)(pb + (b0 + jb) * DEE + d0)     = lo;
        *(float4*)(pb + (b0 + jb) * DEE + d0 + 4) = hi;
    }
}

// ---------------------------------------------------------------------------
// K3: reduce split-K partials, + b_gcn, leaky_relu -> feat (output 1),
//     then output = feat @ w_cls.T + b_cls (output 0). One block per batch.
// ---------------------------------------------------------------------------
__global__ __launch_bounds__(1024) void k_red(
    const float* __restrict__ P, const float* __restrict__ b_gcn,
    const float* __restrict__ w_cls, const float* __restrict__ b_cls,
    float* __restrict__ out)
{
    const int b = blockIdx.x, t = threadIdx.x;
    const int d = t & 127, pg = t >> 7;   // 8 p-groups of 64
    __shared__ float red[8][DEE];
    __shared__ __align__(16) float lf[DEE];

    const float* pp = P + (size_t)pg * 64 * (BB * DEE) + b * DEE + d;
    float a0 = 0.f, a1 = 0.f, a2 = 0.f, a3 = 0.f;
    for (int p = 0; p < 64; p += 4) {
        a0 += pp[(size_t)(p + 0) * (BB * DEE)];
        a1 += pp[(size_t)(p + 1) * (BB * DEE)];
        a2 += pp[(size_t)(p + 2) * (BB * DEE)];
        a3 += pp[(size_t)(p + 3) * (BB * DEE)];
    }
    red[pg][d] = (a0 + a1) + (a2 + a3);
    __syncthreads();
    if (t < DEE) {
        float s = 0.f;
#pragma unroll
        for (int g = 0; g < 8; ++g) s += red[g][t];
        s += b_gcn[t];
        s = lrelu(s);
        out[O_FEAT + b * DEE + t] = s;   // output 1
        lf[t] = s;
    }
    __syncthreads();
    if (t < NCC) {
        float o = b_cls[t];
        const float* wc = w_cls + t * DEE;
        for (int d2 = 0; d2 < DEE; d2 += 4) {
            float4 w4 = *(const float4*)(wc + d2);
            o += w4.x * lf[d2] + w4.y * lf[d2 + 1] + w4.z * lf[d2 + 2] + w4.w * lf[d2 + 3];
        }
        out[b * NCC + t] = o;            // output 0
    }
}

extern "C" void kernel_launch(void* const* d_in, const int* in_sizes, int n_in,
                              void* d_out, int out_size, void* d_ws, size_t ws_size,
                              hipStream_t stream) {
    const float* word_recon    = (const float*)d_in[0];
    const float* beta_p        = (const float*)d_in[1];
    const float* metrix_sl     = (const float*)d_in[2];
    const float* cls_word_prob = (const float*)d_in[3];
    const float* emb           = (const float*)d_in[4];
    const float* w_sl          = (const float*)d_in[5];
    const float* b_sl          = (const float*)d_in[6];
    const float* w_lw          = (const float*)d_in[7];
    const float* b_lw          = (const float*)d_in[8];
    const float* w_gcn         = (const float*)d_in[9];
    const float* b_gcn         = (const float*)d_in[10];
    const float* w_cls         = (const float*)d_in[11];
    const float* b_cls         = (const float*)d_in[12];
    const int*   label         = (const int*)d_in[13];
    const int*   kptr          = (const int*)d_in[14];
    float* out = (float*)d_out;
    float* ws  = (float*)d_ws;

    k1_prep<<<BB, 256, 0, stream>>>(word_recon, metrix_sl, cls_word_prob, emb,
                                    w_sl, b_sl, w_lw, b_lw, label, kptr, out, ws);
    k_fused<<<MM_BLOCKS, 256, 0, stream>>>(w_gcn, beta_p, ws + WS_V, ws + WS_S0,
                                           ws + WS_S1, ws + WS_N1, ws + WS_MHT,
                                           ws + WS_WPT, out + O_WP, out + O_ADJ,
                                           ws + WS_P);
    k_red<<<BB, 1024, 0, stream>>>(ws + WS_P, b_gcn, w_cls, b_cls, out);
}